// Round 1
// baseline (223.418 us; speedup 1.0000x reference)
//
#include <hip/hip_runtime.h>

typedef unsigned int u32;

#define NPS   (256 * 1 * 128 * 128)   // elements per sample = T*C*H*W = 4194304
#define NSAMP 8
#define NB    4096                    // value-histogram buckets
#define PREDN 16384                   // H*W
#define BPS   64                      // blocks per sample in main pass

// ---------------- impute: pred[h][w] = MLP(x_emb[h] * y_emb[w]) ----------------
__global__ __launch_bounds__(256) void impute_kernel(
    const float* __restrict__ xe, const float* __restrict__ ye,
    const float* __restrict__ w1, const float* __restrict__ b1,
    const float* __restrict__ w2, const float* __restrict__ b2,
    float* __restrict__ pred)
{
    __shared__ float sw1[64 * 32];
    __shared__ float sb1[32];
    __shared__ float sw2[32];
    __shared__ float sb2;
    for (int i = threadIdx.x; i < 2048; i += 256) sw1[i] = w1[i];
    if (threadIdx.x < 32) { sb1[threadIdx.x] = b1[threadIdx.x]; sw2[threadIdx.x] = w2[threadIdx.x]; }
    if (threadIdx.x == 0) sb2 = b2[0];
    __syncthreads();

    int t = blockIdx.x * 256 + threadIdx.x;
    if (t >= PREDN) return;
    int h = t >> 7, w = t & 127;

    float acc[32];
#pragma unroll
    for (int j = 0; j < 32; ++j) acc[j] = sb1[j];

    const float* xr = xe + h * 64;
    const float* yr = ye + w * 64;
#pragma unroll 4
    for (int e = 0; e < 64; ++e) {
        float p = xr[e] * yr[e];
#pragma unroll
        for (int j = 0; j < 32; ++j) acc[j] = fmaf(p, sw1[e * 32 + j], acc[j]);
    }
    float o = sb2;
#pragma unroll
    for (int j = 0; j < 32; ++j) {
        float a = acc[j];
        float s = a / (1.0f + expf(-a));   // silu
        o = fmaf(s, sw2[j], o);
    }
    pred[t] = o;
}

// ---------------- main pass: per-sample value histogram {count, sum residual^2} ----------------
__global__ __launch_bounds__(256) void main_pass(
    const float* __restrict__ data, const float* __restrict__ mask,
    const float* __restrict__ rnd, const float* __restrict__ pred,
    u32* __restrict__ hist_cnt, float* __restrict__ hist_sum,
    u32* __restrict__ zc, float* __restrict__ zs)
{
    __shared__ u32   lc[NB];
    __shared__ float ls[NB];
    for (int i = threadIdx.x; i < NB; i += 256) { lc[i] = 0u; ls[i] = 0.0f; }
    __syncthreads();

    const int s = blockIdx.y;
    const int chunk = NPS / BPS;             // 65536
    const int start = blockIdx.x * chunk;
    const size_t base = (size_t)s * NPS + start;

    const float4* d4 = (const float4*)(data + base);
    const float4* m4 = (const float4*)(mask + base);
    const float4* r4 = (const float4*)(rnd + base);

    u32 lzc = 0; float lzs = 0.0f;
    const int nv = chunk / 4;                // 16384
    for (int v = threadIdx.x; v < nv; v += 256) {
        float4 dd = d4[v], mm = m4[v], rr = r4[v];
        int e0 = start + v * 4;
#pragma unroll
        for (int j = 0; j < 4; ++j) {
            float m = (&mm.x)[j];
            if (m != 0.0f) {
                float rm = (&rr.x)[j] * m;
                float resid = (&dd.x)[j] - pred[(e0 + j) & (PREDN - 1)];
                float r2 = resid * resid;
                if (rm > 0.0f) {
                    int b = (int)(rm * (float)NB);
                    b = b < NB ? b : NB - 1;
                    atomicAdd(&lc[b], 1u);
#if defined(__HIP_DEVICE_COMPILE__)
                    unsafeAtomicAdd(&ls[b], r2);
#else
                    atomicAdd(&ls[b], r2);
#endif
                } else { lzc++; lzs += r2; }
            }
        }
    }
    if (lzc) {
        atomicAdd(&zc[s], lzc);
#if defined(__HIP_DEVICE_COMPILE__)
        unsafeAtomicAdd(&zs[s], lzs);
#else
        atomicAdd(&zs[s], lzs);
#endif
    }
    __syncthreads();

    u32*   gc = hist_cnt + s * NB;
    float* gs = hist_sum + s * NB;
    for (int i = threadIdx.x; i < NB; i += 256) {
        u32 c = lc[i];
        if (c) {
            atomicAdd(&gc[i], c);
#if defined(__HIP_DEVICE_COMPILE__)
            unsafeAtomicAdd(&gs[i], ls[i]);
#else
            atomicAdd(&gs[i], ls[i]);
#endif
        }
    }
}

// ---------------- per-sample top-k selection over histogram ----------------
__global__ __launch_bounds__(256) void select_kernel(
    const u32* __restrict__ hist_cnt, const float* __restrict__ hist_sum,
    const u32* __restrict__ zc, const float* __restrict__ zs,
    double* __restrict__ psum, double* __restrict__ pcnt)
{
    const int s = blockIdx.x;
    __shared__ u32   lc[NB];
    __shared__ float ls[NB];
    __shared__ u32   tcnt[256];
    __shared__ float tsum[256];

    const u32*   gc = hist_cnt + s * NB;
    const float* gs = hist_sum + s * NB;
    for (int i = threadIdx.x; i < NB; i += 256) { lc[i] = gc[i]; ls[i] = gs[i]; }
    __syncthreads();

    {   // per-thread chunk of 16 consecutive buckets
        int t = threadIdx.x;
        u32 c = 0; float sm = 0.0f;
#pragma unroll
        for (int i = 0; i < 16; ++i) { c += lc[t * 16 + i]; sm += ls[t * 16 + i]; }
        tcnt[t] = c; tsum[t] = sm;
    }
    __syncthreads();

    if (threadIdx.x == 0) {
        long long tot = 0;
        for (int t = 0; t < 256; ++t) tot += tcnt[t];
        long long zcs = (long long)zc[s];
        float nobs = (float)(tot + zcs);
        long long k = (long long)rintf(nobs * 0.1f);   // matches jnp.round (half-even)
        if (k > tot) k = tot;
        if (k < 0)  k = 0;

        double sel = 0.0; long long cum = 0; int tx = -1;
        for (int t = 255; t >= 0; --t) {
            u32 c = tcnt[t];
            if (cum + (long long)c <= k) { cum += c; sel += (double)tsum[t]; }
            else { tx = t; break; }
        }
        if (tx >= 0) {
            for (int b = tx * 16 + 15; b >= tx * 16; --b) {
                u32 c = lc[b];
                if (cum + (long long)c <= k) { cum += c; sel += (double)ls[b]; }
                else {
                    long long need = k - cum;
                    if (need > 0) sel += (double)ls[b] * ((double)need / (double)c);
                    cum = k;
                    break;
                }
            }
        }
        psum[s] = sel + (double)zs[s];
        pcnt[s] = (double)(cum + zcs);
    }
}

__global__ void finalize_kernel(const double* __restrict__ psum,
                                const double* __restrict__ pcnt,
                                float* __restrict__ out)
{
    if (blockIdx.x == 0 && threadIdx.x == 0) {
        double S = 0.0, C = 0.0;
        for (int i = 0; i < NSAMP; ++i) { S += psum[i]; C += pcnt[i]; }
        out[0] = (float)(S / (C > 0.0 ? C : 1.0));
    }
}

extern "C" void kernel_launch(void* const* d_in, const int* in_sizes, int n_in,
                              void* d_out, int out_size, void* d_ws, size_t ws_size,
                              hipStream_t stream)
{
    // setup_inputs order:
    // 0 observed_data [8,256,1,128,128] f32
    // 1 observed_mask  same
    // 2 observed_y, 3 observed_y_mask (unused)
    // 4 rand_vals     same as data
    // 5 x_emb [128,64], 6 y_emb [128,64]
    // 7 w1 [64,32], 8 b1 [32], 9 w2 [32,1], 10 b2 [1], 11 is_train (unused)
    const float* data = (const float*)d_in[0];
    const float* mask = (const float*)d_in[1];
    const float* rnd  = (const float*)d_in[4];
    const float* xe   = (const float*)d_in[5];
    const float* ye   = (const float*)d_in[6];
    const float* w1   = (const float*)d_in[7];
    const float* b1   = (const float*)d_in[8];
    const float* w2   = (const float*)d_in[9];
    const float* b2   = (const float*)d_in[10];
    float* out = (float*)d_out;

    char* ws = (char*)d_ws;
    float*  pred     = (float*)(ws);                        // 65536 B
    u32*    hist_cnt = (u32*)(ws + 65536);                  // 131072 B
    float*  hist_sum = (float*)(ws + 65536 + 131072);       // 131072 B
    u32*    zcp      = (u32*)(ws + 327680);                 // 32 B
    float*  zsp      = (float*)(ws + 327712);               // 32 B
    double* psum     = (double*)(ws + 327744);              // 64 B
    double* pcnt     = (double*)(ws + 327808);              // 64 B

    hipMemsetAsync(ws + 65536, 0, 262144 + 64, stream);

    impute_kernel<<<(PREDN + 255) / 256, 256, 0, stream>>>(xe, ye, w1, b1, w2, b2, pred);

    dim3 grid(BPS, NSAMP);
    main_pass<<<grid, 256, 0, stream>>>(data, mask, rnd, pred, hist_cnt, hist_sum, zcp, zsp);

    select_kernel<<<NSAMP, 256, 0, stream>>>(hist_cnt, hist_sum, zcp, zsp, psum, pcnt);
    finalize_kernel<<<1, 64, 0, stream>>>(psum, pcnt, out);
}